// Round 7
// baseline (2566.440 us; speedup 1.0000x reference)
//
#include <hip/hip_runtime.h>

// SNN forward, bit-exact replication of a numpy float32 reference:
// all contractions are ascending-k single-accumulator f32 chains (fma for
// x@w1, rounded adds of spiking rows for spk@v / spk@w2), elementwise ops
// rounded per-op in np's order. B=128, T=500, NIN=256, NH=512, NOUT=20.

#define B_    128
#define T_    500
#define NIN_  256
#define NH_   512
#define NOUT_ 20

typedef float f32x4 __attribute__((ext_vector_type(4)));

// float(np.exp(-0.1)), float(np.exp(-0.2)): f64 value then cast to f32
#define BETA_F  ((float)0.9048374180359595731642490594464366)
#define ALPHA_F ((float)0.8187307530779818586699355086190395)

// ---------------------------------------------------------------------------
// Vp[513][512] = V + zero row; W2p[513][20] = W2 + zero row (pad gather)
// ---------------------------------------------------------------------------
__global__ __launch_bounds__(256)
void pad_vw(const float* __restrict__ V, const float* __restrict__ W2,
            float* __restrict__ Vp, float* __restrict__ W2p)
{
    const int i = blockIdx.x * 256 + threadIdx.x;
    if (i < 513 * 512) Vp[i]  = (i < 512 * 512) ? V[i]  : 0.f;
    if (i < 513 * 20)  W2p[i] = (i < 512 * 20)  ? W2[i] : 0.f;
}

// ---------------------------------------------------------------------------
// Kernel A: H[M,N] = X[M,K] @ W[K,N], K=256, N=512, f32.
// Per-element: single accumulator, ascending k, one __fmaf_rn per k —
// bit-identical to numpy einsum (FMA3) / BLAS sgemm chains.
// BM=BN=128, BK=16, 256 threads, 8x8 micro-tile, double-buffered LDS.
// ---------------------------------------------------------------------------
__global__ __launch_bounds__(256)
void gemm_h1(const float* __restrict__ X, const float* __restrict__ W,
             float* __restrict__ H)
{
    __shared__ float As[2][16][132];   // [buf][k][m] (transposed)
    __shared__ float Bs[2][16][132];   // [buf][k][n]

    const int tid = threadIdx.x;
    const int bn = blockIdx.x & 3;          // N/128 = 4
    const int bm = blockIdx.x >> 2;
    const int m0 = bm * 128, n0 = bn * 128;
    const int tx = tid & 15, ty = tid >> 4;

    const int ar = tid >> 2;                // 0..63
    const int ac = (tid & 3) << 2;          // 0,4,8,12
    const int br = tid >> 5;                // 0..7
    const int bc = (tid & 31) << 2;         // 0..124

    const float* Xa0 = X + (size_t)(m0 + ar)      * NIN_ + ac;
    const float* Xa1 = X + (size_t)(m0 + ar + 64) * NIN_ + ac;
    const float* Wb0 = W + (size_t)br       * NH_ + n0 + bc;
    const float* Wb1 = W + (size_t)(br + 8) * NH_ + n0 + bc;

    float acc[8][8] = {};

    float4 a0 = *(const float4*)(Xa0);
    float4 a1 = *(const float4*)(Xa1);
    float4 b0 = *(const float4*)(Wb0);
    float4 b1 = *(const float4*)(Wb1);

    As[0][ac + 0][ar] = a0.x; As[0][ac + 1][ar] = a0.y;
    As[0][ac + 2][ar] = a0.z; As[0][ac + 3][ar] = a0.w;
    As[0][ac + 0][ar + 64] = a1.x; As[0][ac + 1][ar + 64] = a1.y;
    As[0][ac + 2][ar + 64] = a1.z; As[0][ac + 3][ar + 64] = a1.w;
    *(float4*)&Bs[0][br][bc]     = b0;
    *(float4*)&Bs[0][br + 8][bc] = b1;
    __syncthreads();

    int cur = 0;
    for (int kt = 0; kt < NIN_; kt += 16) {
        const bool more = (kt + 16) < NIN_;
        if (more) {
            a0 = *(const float4*)(Xa0 + kt + 16);
            a1 = *(const float4*)(Xa1 + kt + 16);
            b0 = *(const float4*)(Wb0 + (size_t)(kt + 16) * NH_);
            b1 = *(const float4*)(Wb1 + (size_t)(kt + 16) * NH_);
        }
#pragma unroll
        for (int kk = 0; kk < 16; ++kk) {
            const float4 av0 = *(const float4*)&As[cur][kk][ty * 8];
            const float4 av1 = *(const float4*)&As[cur][kk][ty * 8 + 4];
            const float4 bv0 = *(const float4*)&Bs[cur][kk][tx * 8];
            const float4 bv1 = *(const float4*)&Bs[cur][kk][tx * 8 + 4];
            const float a_[8] = {av0.x, av0.y, av0.z, av0.w, av1.x, av1.y, av1.z, av1.w};
            const float b_[8] = {bv0.x, bv0.y, bv0.z, bv0.w, bv1.x, bv1.y, bv1.z, bv1.w};
#pragma unroll
            for (int i = 0; i < 8; ++i)
#pragma unroll
                for (int j = 0; j < 8; ++j)
                    acc[i][j] = __fmaf_rn(a_[i], b_[j], acc[i][j]);
        }
        if (more) {
            const int nx = cur ^ 1;
            As[nx][ac + 0][ar] = a0.x; As[nx][ac + 1][ar] = a0.y;
            As[nx][ac + 2][ar] = a0.z; As[nx][ac + 3][ar] = a0.w;
            As[nx][ac + 0][ar + 64] = a1.x; As[nx][ac + 1][ar + 64] = a1.y;
            As[nx][ac + 2][ar + 64] = a1.z; As[nx][ac + 3][ar + 64] = a1.w;
            *(float4*)&Bs[nx][br][bc]     = b0;
            *(float4*)&Bs[nx][br + 8][bc] = b1;
            __syncthreads();
            cur = nx;
        }
    }

#pragma unroll
    for (int i = 0; i < 8; ++i) {
        float* dst = H + (size_t)(m0 + ty * 8 + i) * NH_ + n0 + tx * 8;
        f32x4 v0 = {acc[i][0], acc[i][1], acc[i][2], acc[i][3]};
        f32x4 v1 = {acc[i][4], acc[i][5], acc[i][6], acc[i][7]};
        __builtin_nontemporal_store(v0, (f32x4*)dst);
        __builtin_nontemporal_store(v1, (f32x4*)(dst + 4));
    }
}

// ---------------------------------------------------------------------------
// Kernel B: sequential LIF scan, f32, np-exact rounding. One WG per batch
// element, 512 threads. Per step: ballot -> ordered compaction (ascending h)
// -> serial ascending f32 add chain over spiking V rows (and W2 rows for
// threads 0..19), software-pipelined in static-unrolled batches of 32.
// ---------------------------------------------------------------------------
__global__ __launch_bounds__(512)
void snn_scan(const float* __restrict__ H, const float* __restrict__ Vp,
              const float* __restrict__ W2p, float* __restrict__ OUT)
{
    const int b = blockIdx.x;
    const int h = threadIdx.x;
    const int lane = h & 63;
    const int wv = h >> 6;

    __shared__ __align__(16) unsigned smask[16];
    __shared__ unsigned short slist[768];   // compacted rows + pad

    if (h < 256) slist[512 + h] = (unsigned short)NH_;   // static pad (once)

    float syn = 0.f, mem = 0.f, flt = 0.f, outm = 0.f;
    const float* __restrict__ Hb = H + (size_t)b * T_ * NH_;
    float* __restrict__ Ob = OUT + (size_t)b * T_ * NOUT_;
    const bool ro = (h < NOUT_);
    const float* __restrict__ W2c = W2p + h;   // column o = h (ro threads)

    float h1v = Hb[h];
    __syncthreads();   // static pad visible before first gather

    for (int t = 0; t < T_; ++t) {
        // ---- P1: spike + ballot ----
        const bool spk = mem > 1.0f;                 // == (mem - 1.0f > 0)
        const unsigned long long bal = __ballot(spk);
        if (lane == 0) {
            smask[(wv << 1) + 0] = (unsigned)bal;
            smask[(wv << 1) + 1] = (unsigned)(bal >> 32);
        }
        __syncthreads();                             // S1

        // ---- P2: count + ordered compaction + per-step pad ----
        const uint4 q0 = *(const uint4*)&smask[0];
        const uint4 q1 = *(const uint4*)&smask[4];
        const uint4 q2 = *(const uint4*)&smask[8];
        const uint4 q3 = *(const uint4*)&smask[12];
        const unsigned wb16[16] = {q0.x,q0.y,q0.z,q0.w, q1.x,q1.y,q1.z,q1.w,
                                   q2.x,q2.y,q2.z,q2.w, q3.x,q3.y,q3.z,q3.w};
        int cnt = 0;
#pragma unroll
        for (int i = 0; i < 16; ++i) cnt += __popc(wb16[i]);

        int off = 0;
#pragma unroll
        for (int j = 0; j < 8; ++j) {
            const int cj = __popc(wb16[2*j]) + __popc(wb16[2*j + 1]);
            off += (j < wv) ? cj : 0;
        }
        if (spk) {   // rank within wave = popcount of lower lanes (ascending)
            const int idx = __popcll(bal & ((1ull << (unsigned)lane) - 1ull));
            slist[off + idx] = (unsigned short)h;
        }
        if (h >= cnt) slist[h] = (unsigned short)NH_;   // pad [cnt,512)

        const float h1n = (t + 1 < T_) ? Hb[(size_t)(t + 1) * NH_ + h] : 0.f;
        __syncthreads();                             // S2

        // ---- P3: serial ascending add chains (np sgemm order), pipelined ----
        float acc = 0.f, acc2 = 0.f;
        const int nr = (cnt + 63) & ~63;
        if (nr) {
            int ra[32], rb[32];
            float va[32], vb[32], wa[32], wc[32];
#pragma unroll
            for (int q = 0; q < 32; ++q) ra[q] = slist[q];
#pragma unroll
            for (int q = 0; q < 32; ++q) va[q] = Vp[((size_t)ra[q] << 9) + h];
            if (ro) {
#pragma unroll
                for (int q = 0; q < 32; ++q) wa[q] = W2c[(size_t)ra[q] * NOUT_];
            }
            for (int j = 0; j < nr; j += 64) {
#pragma unroll
                for (int q = 0; q < 32; ++q) rb[q] = slist[j + 32 + q];
#pragma unroll
                for (int q = 0; q < 32; ++q) vb[q] = Vp[((size_t)rb[q] << 9) + h];
                if (ro) {
#pragma unroll
                    for (int q = 0; q < 32; ++q) wc[q] = W2c[(size_t)rb[q] * NOUT_];
                }
#pragma unroll
                for (int q = 0; q < 32; ++q) acc = __fadd_rn(acc, va[q]);
                if (ro) {
#pragma unroll
                    for (int q = 0; q < 32; ++q) acc2 = __fadd_rn(acc2, wa[q]);
                }
#pragma unroll
                for (int q = 0; q < 32; ++q) ra[q] = slist[j + 64 + q];   // <= 543 < 768
#pragma unroll
                for (int q = 0; q < 32; ++q) va[q] = Vp[((size_t)ra[q] << 9) + h];
                if (ro) {
#pragma unroll
                    for (int q = 0; q < 32; ++q) wa[q] = W2c[(size_t)ra[q] * NOUT_];
                }
#pragma unroll
                for (int q = 0; q < 32; ++q) acc = __fadd_rn(acc, vb[q]);
                if (ro) {
#pragma unroll
                    for (int q = 0; q < 32; ++q) acc2 = __fadd_rn(acc2, wc[q]);
                }
            }
        }

        // ---- state update, np per-op rounding order ----
        const float memb = __fadd_rn(__fmul_rn(BETA_F, mem), syn);  // OLD syn
        mem = spk ? 0.0f : memb;
        syn = __fadd_rn(__fadd_rn(__fmul_rn(ALPHA_F, syn), h1v), acc);
        h1v = h1n;

        if (ro) {
            flt  = __fadd_rn(__fmul_rn(ALPHA_F, flt), acc2);
            outm = __fadd_rn(__fmul_rn(BETA_F, outm), flt);
            Ob[(size_t)t * NOUT_ + h] = outm;
        }
    }
}

// ---------------------------------------------------------------------------
extern "C" void kernel_launch(void* const* d_in, const int* in_sizes, int n_in,
                              void* d_out, int out_size, void* d_ws, size_t ws_size,
                              hipStream_t stream)
{
    const float* x  = (const float*)d_in[0];   // [B, T, NIN]
    const float* w1 = (const float*)d_in[1];   // [NIN, NH]
    const float* v  = (const float*)d_in[2];   // [NH, NH]
    const float* w2 = (const float*)d_in[3];   // [NH, NOUT]
    float* out = (float*)d_out;                // [B, T, NOUT]

    float* vp  = (float*)d_ws;                                   // [513][512]
    float* w2p = vp + 513 * 512;                                 // [513][20]
    float* h1  = (float*)((char*)d_ws + 1091712);                // [chunk*T][NH]

    pad_vw<<<dim3((513 * 512 + 255) / 256), dim3(256), 0, stream>>>(v, w2, vp, w2p);

    const size_t need_full = 1091712 + (size_t)B_ * T_ * NH_ * 4;
    // chunk must be a multiple of 32 so M = chunk*T_ is divisible by 128
    const int chunk = (ws_size >= need_full) ? B_ : 32;

    for (int b0 = 0; b0 < B_; b0 += chunk) {
        const int nb = (B_ - b0 < chunk) ? (B_ - b0) : chunk;
        const int M = nb * T_;
        gemm_h1<<<dim3((M / 128) * (NH_ / 128)), dim3(256), 0, stream>>>(
            x + (size_t)b0 * T_ * NIN_, w1, h1);
        snn_scan<<<dim3(nb), dim3(512), 0, stream>>>(
            h1, vp, w2p, out + (size_t)b0 * T_ * NOUT_);
    }
}

// Round 12
// 1818.270 us; speedup vs baseline: 1.4115x; 1.4115x over previous
//
#include <hip/hip_runtime.h>

// SNN forward, bit-exact vs numpy f32 reference (ascending-k single-
// accumulator chains). GEMM near roofline; this round: scan pipeline depth
// (forced with sched_barrier) + dedicated readout wave (576-thread WG).
// B=128, T=500, NIN=256, NH=512, NOUT=20.

#define B_    128
#define T_    500
#define NIN_  256
#define NH_   512
#define NOUT_ 20

typedef float f32x4 __attribute__((ext_vector_type(4)));

// float(np.exp(-0.1)), float(np.exp(-0.2))
#define BETA_F  ((float)0.9048374180359595731642490594464366)
#define ALPHA_F ((float)0.8187307530779818586699355086190395)

// ---------------------------------------------------------------------------
// Vp[513][512] = V + zero row; W2p[513][20] = W2 + zero row (pad gather)
// ---------------------------------------------------------------------------
__global__ __launch_bounds__(256)
void pad_vw(const float* __restrict__ V, const float* __restrict__ W2,
            float* __restrict__ Vp, float* __restrict__ W2p)
{
    const int i = blockIdx.x * 256 + threadIdx.x;
    if (i < 513 * 512) Vp[i]  = (i < 512 * 512) ? V[i]  : 0.f;
    if (i < 513 * 20)  W2p[i] = (i < 512 * 20)  ? W2[i] : 0.f;
}

// ---------------------------------------------------------------------------
// Kernel A: H[M,N] = X[M,K] @ W[K,N], K=256, N=512, f32, ascending-k fma
// chain per element (np-exact). BM=BN=128, BK=16, 256 thr, 8x8 micro-tile,
// double-buffered LDS. ~near f32 VALU roofline already.
// ---------------------------------------------------------------------------
__global__ __launch_bounds__(256)
void gemm_h1(const float* __restrict__ X, const float* __restrict__ W,
             float* __restrict__ H)
{
    __shared__ float As[2][16][132];   // [buf][k][m] (transposed)
    __shared__ float Bs[2][16][132];   // [buf][k][n]

    const int tid = threadIdx.x;
    const int bn = blockIdx.x & 3;
    const int bm = blockIdx.x >> 2;
    const int m0 = bm * 128, n0 = bn * 128;
    const int tx = tid & 15, ty = tid >> 4;

    const int ar = tid >> 2;
    const int ac = (tid & 3) << 2;
    const int br = tid >> 5;
    const int bc = (tid & 31) << 2;

    const float* Xa0 = X + (size_t)(m0 + ar)      * NIN_ + ac;
    const float* Xa1 = X + (size_t)(m0 + ar + 64) * NIN_ + ac;
    const float* Wb0 = W + (size_t)br       * NH_ + n0 + bc;
    const float* Wb1 = W + (size_t)(br + 8) * NH_ + n0 + bc;

    float acc[8][8] = {};

    float4 a0 = *(const float4*)(Xa0);
    float4 a1 = *(const float4*)(Xa1);
    float4 b0 = *(const float4*)(Wb0);
    float4 b1 = *(const float4*)(Wb1);

    As[0][ac + 0][ar] = a0.x; As[0][ac + 1][ar] = a0.y;
    As[0][ac + 2][ar] = a0.z; As[0][ac + 3][ar] = a0.w;
    As[0][ac + 0][ar + 64] = a1.x; As[0][ac + 1][ar + 64] = a1.y;
    As[0][ac + 2][ar + 64] = a1.z; As[0][ac + 3][ar + 64] = a1.w;
    *(float4*)&Bs[0][br][bc]     = b0;
    *(float4*)&Bs[0][br + 8][bc] = b1;
    __syncthreads();

    int cur = 0;
    for (int kt = 0; kt < NIN_; kt += 16) {
        const bool more = (kt + 16) < NIN_;
        if (more) {
            a0 = *(const float4*)(Xa0 + kt + 16);
            a1 = *(const float4*)(Xa1 + kt + 16);
            b0 = *(const float4*)(Wb0 + (size_t)(kt + 16) * NH_);
            b1 = *(const float4*)(Wb1 + (size_t)(kt + 16) * NH_);
        }
#pragma unroll
        for (int kk = 0; kk < 16; ++kk) {
            const float4 av0 = *(const float4*)&As[cur][kk][ty * 8];
            const float4 av1 = *(const float4*)&As[cur][kk][ty * 8 + 4];
            const float4 bv0 = *(const float4*)&Bs[cur][kk][tx * 8];
            const float4 bv1 = *(const float4*)&Bs[cur][kk][tx * 8 + 4];
            const float a_[8] = {av0.x, av0.y, av0.z, av0.w, av1.x, av1.y, av1.z, av1.w};
            const float b_[8] = {bv0.x, bv0.y, bv0.z, bv0.w, bv1.x, bv1.y, bv1.z, bv1.w};
#pragma unroll
            for (int i = 0; i < 8; ++i)
#pragma unroll
                for (int j = 0; j < 8; ++j)
                    acc[i][j] = __fmaf_rn(a_[i], b_[j], acc[i][j]);
        }
        if (more) {
            const int nx = cur ^ 1;
            As[nx][ac + 0][ar] = a0.x; As[nx][ac + 1][ar] = a0.y;
            As[nx][ac + 2][ar] = a0.z; As[nx][ac + 3][ar] = a0.w;
            As[nx][ac + 0][ar + 64] = a1.x; As[nx][ac + 1][ar + 64] = a1.y;
            As[nx][ac + 2][ar + 64] = a1.z; As[nx][ac + 3][ar + 64] = a1.w;
            *(float4*)&Bs[nx][br][bc]     = b0;
            *(float4*)&Bs[nx][br + 8][bc] = b1;
            __syncthreads();
            cur = nx;
        }
    }

#pragma unroll
    for (int i = 0; i < 8; ++i) {
        float* dst = H + (size_t)(m0 + ty * 8 + i) * NH_ + n0 + tx * 8;
        f32x4 v0 = {acc[i][0], acc[i][1], acc[i][2], acc[i][3]};
        f32x4 v1 = {acc[i][4], acc[i][5], acc[i][6], acc[i][7]};
        __builtin_nontemporal_store(v0, (f32x4*)dst);
        __builtin_nontemporal_store(v1, (f32x4*)(dst + 4));
    }
}

// ---------------------------------------------------------------------------
// Kernel B: sequential LIF scan, f32, np-exact rounding. One WG per batch,
// 576 threads: tid<512 own a hidden column (V chain); tid 512..531 own a
// readout column (W2 chain, dedicated wave 8); rest idle. Per step:
// ballot -> ordered compaction -> serial ascending f32 add chain, forced
// 3-buffer x 32-row pipeline (sched_barrier pins), uniform guards.
// ---------------------------------------------------------------------------
#define LOADG(VV, J)                                                         \
    {                                                                        \
        const int jj_ = (J);                                                 \
        int ii_[32];                                                         \
        _Pragma("unroll")                                                    \
        for (int q = 0; q < 32; ++q) ii_[q] = slist[jj_ + q];                \
        _Pragma("unroll")                                                    \
        for (int q = 0; q < 32; ++q)                                         \
            VV[q] = gbase[(size_t)((unsigned)ii_[q] * (unsigned)gstride)];   \
        __builtin_amdgcn_sched_barrier(0);                                   \
    }

#define ADDG(VV)                                                             \
    {                                                                        \
        _Pragma("unroll")                                                    \
        for (int q = 0; q < 32; ++q) acc = __fadd_rn(acc, VV[q]);            \
        __builtin_amdgcn_sched_barrier(0);                                   \
    }

__global__ __launch_bounds__(576)
void snn_scan(const float* __restrict__ H, const float* __restrict__ Vp,
              const float* __restrict__ W2p, float* __restrict__ OUT)
{
    const int b = blockIdx.x;
    const int h = threadIdx.x;
    const int lane = h & 63;
    const int wv = h >> 6;
    const bool isCol = (h < NH_);
    const bool isRo  = (h >= NH_) && (h < NH_ + NOUT_);

    __shared__ __align__(16) unsigned smask[16];
    __shared__ unsigned short slist[NH_];

    float syn = 0.f, mem = 0.f, flt = 0.f, outm = 0.f;
    const float* __restrict__ Hb = H + (size_t)b * T_ * NH_;
    float* __restrict__ Ob = OUT + (size_t)b * T_ * NOUT_;

    // unified gather: column threads walk Vp column h; readout threads walk
    // W2p column (h-512); idle threads walk the zero row (stride 0).
    const float* gbase;
    int gstride;
    if (isCol)     { gbase = Vp + h;                  gstride = NH_;   }
    else if (isRo) { gbase = W2p + (h - NH_);         gstride = NOUT_; }
    else           { gbase = Vp + (size_t)NH_ * NH_;  gstride = 0;     }

    float h1v = isCol ? Hb[h] : 0.f;

    for (int t = 0; t < T_; ++t) {
        // ---- P1: spike + ballot ----
        const bool spk = isCol && (mem > 1.0f);      // == (mem - 1.0f > 0)
        const unsigned long long bal = __ballot(spk);
        if (lane == 0 && wv < 8) {
            smask[(wv << 1) + 0] = (unsigned)bal;
            smask[(wv << 1) + 1] = (unsigned)(bal >> 32);
        }
        __syncthreads();                             // S1

        // ---- P2: count + ordered compaction + pad + h1 prefetch ----
        const uint4 q0 = *(const uint4*)&smask[0];
        const uint4 q1 = *(const uint4*)&smask[4];
        const uint4 q2 = *(const uint4*)&smask[8];
        const uint4 q3 = *(const uint4*)&smask[12];
        const unsigned wb16[16] = {q0.x,q0.y,q0.z,q0.w, q1.x,q1.y,q1.z,q1.w,
                                   q2.x,q2.y,q2.z,q2.w, q3.x,q3.y,q3.z,q3.w};
        int cnt = 0;
#pragma unroll
        for (int i = 0; i < 16; ++i) cnt += __popc(wb16[i]);

        int off = 0;
#pragma unroll
        for (int j = 0; j < 8; ++j) {
            const int cj = __popc(wb16[2*j]) + __popc(wb16[2*j + 1]);
            off += (j < wv) ? cj : 0;
        }
        if (spk) {   // ascending rank within wave
            const int idx = __popcll(bal & ((1ull << (unsigned)lane) - 1ull));
            slist[off + idx] = (unsigned short)h;
        }
        if (isCol && h >= cnt) slist[h] = (unsigned short)NH_;  // pad -> zero row

        const float h1n = (isCol && (t + 1 < T_)) ? Hb[(size_t)(t + 1) * NH_ + h] : 0.f;
        __syncthreads();                             // S2

        // ---- P3: serial ascending add chain, forced-depth pipeline ----
        float acc = 0.f;
        const int NR = (cnt + 31) & ~31;             // uniform across WG
        {
            float vA[32], vB[32], vC[32];
            if (NR > 0)  LOADG(vA, 0);
            if (NR > 32) LOADG(vB, 32);
            if (NR > 64) LOADG(vC, 64);
            for (int j = 0; j < NR; j += 96) {
                ADDG(vA);
                if (j + 96 < NR)  LOADG(vA, j + 96);
                if (j + 32 < NR)  ADDG(vB);
                if (j + 128 < NR) LOADG(vB, j + 128);
                if (j + 64 < NR)  ADDG(vC);
                if (j + 160 < NR) LOADG(vC, j + 160);
            }
        }

        // ---- state update, np per-op rounding order ----
        if (isCol) {
            const float memb = __fadd_rn(__fmul_rn(BETA_F, mem), syn);  // OLD syn
            mem = spk ? 0.0f : memb;
            syn = __fadd_rn(__fadd_rn(__fmul_rn(ALPHA_F, syn), h1v), acc);
            h1v = h1n;
        } else if (isRo) {
            flt  = __fadd_rn(__fmul_rn(ALPHA_F, flt), acc);
            outm = __fadd_rn(__fmul_rn(BETA_F, outm), flt);
            Ob[(size_t)t * NOUT_ + (h - NH_)] = outm;
        }
    }
}

// ---------------------------------------------------------------------------
extern "C" void kernel_launch(void* const* d_in, const int* in_sizes, int n_in,
                              void* d_out, int out_size, void* d_ws, size_t ws_size,
                              hipStream_t stream)
{
    const float* x  = (const float*)d_in[0];   // [B, T, NIN]
    const float* w1 = (const float*)d_in[1];   // [NIN, NH]
    const float* v  = (const float*)d_in[2];   // [NH, NH]
    const float* w2 = (const float*)d_in[3];   // [NH, NOUT]
    float* out = (float*)d_out;                // [B, T, NOUT]

    float* vp  = (float*)d_ws;                                   // [513][512]
    float* w2p = vp + 513 * 512;                                 // [513][20]
    float* h1  = (float*)((char*)d_ws + 1091712);                // [chunk*T][NH]

    pad_vw<<<dim3((513 * 512 + 255) / 256), dim3(256), 0, stream>>>(v, w2, vp, w2p);

    const size_t need_full = 1091712 + (size_t)B_ * T_ * NH_ * 4;
    // chunk multiple of 32 so M = chunk*T_ is divisible by 128
    const int chunk = (ws_size >= need_full) ? B_ : 32;

    for (int b0 = 0; b0 < B_; b0 += chunk) {
        const int nb = (B_ - b0 < chunk) ? (B_ - b0) : chunk;
        const int M = nb * T_;
        gemm_h1<<<dim3((M / 128) * (NH_ / 128)), dim3(256), 0, stream>>>(
            x + (size_t)b0 * T_ * NIN_, w1, h1);
        snn_scan<<<dim3(nb), dim3(576), 0, stream>>>(
            h1, vp, w2p, out + (size_t)b0 * T_ * NOUT_);
    }
}